// Round 14
// baseline (214.283 us; speedup 1.0000x reference)
//
#include <hip/hip_runtime.h>
#include <hip/hip_fp16.h>

#define NV 8
#define NQ 4096
#define C_ 256
#define HEADS 8
#define PTS 4
#define HV 23
#define WV 46
#define NPIX (HV*WV)       // 1058
#define BS 8
#define NROW (BS*NQ)       // 32768
#define NVBLK2 ((BS*NPIX)/16) // 529 value blocks (16 rows each)
#define NQBLK (NROW/16)       // 2048 query blocks

typedef unsigned short ushort_t;
typedef unsigned int uint_t;
typedef float float2v __attribute__((ext_vector_type(2)));

// packed f32 FMA: ACC(pair) += V(pair) * W(pair) -- IEEE-identical per lane
#define PKFMA(ACC, V, W) asm("v_pk_fma_f32 %0, %1, %2, %0" : "+v"(ACC) : "v"(V), "v"(W))

// ---------------- prep (65 blocks): 0..63 WvWout = Wv@Wout; 64: wp2f = Wout@Wp, bvW = bv@Wout, cnt=0 ----------------
__global__ void prep_kernel(const float* __restrict__ Wout, const float* __restrict__ Wp,
                            const float* __restrict__ Wv, const float* __restrict__ bv,
                            float* __restrict__ WvWout, float* __restrict__ wp2f,
                            float* __restrict__ bvW, int* __restrict__ cnt) {
    int blk = blockIdx.x;
    int t = threadIdx.x;
    __shared__ float rows[4][C_];
    if (blk < 64) {
        int r0 = blk * 4;
        #pragma unroll
        for (int r = 0; r < 4; ++r) rows[r][t] = Wv[(r0 + r) * C_ + t];
        __syncthreads();
        float acc[4] = {0.f, 0.f, 0.f, 0.f};
        for (int k = 0; k < C_; ++k) {
            float w = Wout[k * C_ + t];
            acc[0] = fmaf(rows[0][k], w, acc[0]);
            acc[1] = fmaf(rows[1][k], w, acc[1]);
            acc[2] = fmaf(rows[2][k], w, acc[2]);
            acc[3] = fmaf(rows[3][k], w, acc[3]);
        }
        #pragma unroll
        for (int r = 0; r < 4; ++r) WvWout[(r0 + r) * C_ + t] = acc[r];
    } else {
        if (t == 0) *cnt = 0;
        float a = 0.f;
        for (int c = 0; c < C_; ++c) a = fmaf(Wout[t * C_ + c], Wp[c], a);
        wp2f[t] = a;
        float fb = 0.f;
        for (int d = 0; d < C_; ++d) fb = fmaf(bv[d], Wout[d * C_ + t], fb);
        bvW[t] = fb;
    }
}

// ---------------- proj: value blocks (rows-per-wave: 4x fewer broadcast ds_reads) + quad S32Q; query blocks ----------------
// Wave w owns rows 4w..4w+3, lane l owns cols 4l..4l+3. Per k4-iter the wave reads only ITS two
// row-pairs (4 b128 broadcasts, was 16). Weights arrive as per-lane float4 (same request count,
// L2-resident). Col-paired pk-FMA takes weight pairs straight from the float4 halves.
// Per-(row,col) chains keep exact sequential-k order -> v2d/VW bit-identical; S32 partial-sum
// order changes (in-lane 4-add + 8-lane tree) -> ~1e-7 logit noise, absorbed by 1e-4 gap test.
__global__ void proj_kernel(const float* __restrict__ value, const float* __restrict__ Wv,
                            const float* __restrict__ bv, const float* __restrict__ WvWout,
                            const float* __restrict__ bvW, const float* __restrict__ wp2f,
                            const float* __restrict__ query,
                            const float* __restrict__ Wo, const float* __restrict__ bo,
                            const float* __restrict__ Wa, const float* __restrict__ ba,
                            float* __restrict__ v2d, ushort_t* __restrict__ VW,
                            float* __restrict__ S32Q, float* __restrict__ offn,
                            float* __restrict__ attn) {
#pragma clang fp contract(off)
    __shared__ __align__(16) float sbuf[16 * C_ + 16 * 32];
    int blk = blockIdx.x;
    int t = threadIdx.x;
    if (blk < NVBLK2) {
        // ===== value part =====
        int r0 = blk * 16;
        #pragma unroll
        for (int i = 0; i < 16; ++i) {
            int idx = t + i * 256;
            int row = idx >> 8, col = idx & 255;
            sbuf[((row >> 1) << 9) + (col << 1) + (row & 1)] = value[(size_t)r0 * C_ + idx];
        }
        __syncthreads();
        int wvid = t >> 6, l = t & 63;
        int c0 = l * 4;
        int prA = 2 * wvid, prB = 2 * wvid + 1;     // row pairs -> rows 4w..4w+3
        // accL[r] = cols (c0,c0+1), accH[r] = cols (c0+2,c0+3) for row r of this wave
        float2v accL[4], accH[4], accWL[4], accWH[4];
        #pragma unroll
        for (int r = 0; r < 4; ++r) {
            accL[r] = (float2v){0.f, 0.f}; accH[r] = (float2v){0.f, 0.f};
            accWL[r] = (float2v){0.f, 0.f}; accWH[r] = (float2v){0.f, 0.f};
        }
        const float4* ldsq = (const float4*)sbuf;
        for (int k4 = 0; k4 < C_ / 4; ++k4) {
            int k = k4 * 4;
            const float4 qa0 = ldsq[prA * 128 + 2 * k4];       // {r0[k],r1[k],r0[k+1],r1[k+1]}
            const float4 qa1 = ldsq[prA * 128 + 2 * k4 + 1];   // k+2,k+3
            const float4 qb0 = ldsq[prB * 128 + 2 * k4];
            const float4 qb1 = ldsq[prB * 128 + 2 * k4 + 1];
            const float4 wv0 = *(const float4*)(Wv + (size_t)(k + 0) * C_ + c0);
            const float4 wv1 = *(const float4*)(Wv + (size_t)(k + 1) * C_ + c0);
            const float4 wv2 = *(const float4*)(Wv + (size_t)(k + 2) * C_ + c0);
            const float4 wv3 = *(const float4*)(Wv + (size_t)(k + 3) * C_ + c0);
            const float4 uv0 = *(const float4*)(WvWout + (size_t)(k + 0) * C_ + c0);
            const float4 uv1 = *(const float4*)(WvWout + (size_t)(k + 1) * C_ + c0);
            const float4 uv2 = *(const float4*)(WvWout + (size_t)(k + 2) * C_ + c0);
            const float4 uv3 = *(const float4*)(WvWout + (size_t)(k + 3) * C_ + c0);
            // value scalars per (row, k+i)
            float vs[4][4];
            vs[0][0] = qa0.x; vs[1][0] = qa0.y; vs[2][0] = qb0.x; vs[3][0] = qb0.y;   // k
            vs[0][1] = qa0.z; vs[1][1] = qa0.w; vs[2][1] = qb0.z; vs[3][1] = qb0.w;   // k+1
            vs[0][2] = qa1.x; vs[1][2] = qa1.y; vs[2][2] = qb1.x; vs[3][2] = qb1.y;   // k+2
            vs[0][3] = qa1.z; vs[1][3] = qa1.w; vs[2][3] = qb1.z; vs[3][3] = qb1.w;   // k+3
            const float2v wlo[4] = {{wv0.x, wv0.y}, {wv1.x, wv1.y}, {wv2.x, wv2.y}, {wv3.x, wv3.y}};
            const float2v whi[4] = {{wv0.z, wv0.w}, {wv1.z, wv1.w}, {wv2.z, wv2.w}, {wv3.z, wv3.w}};
            const float2v ulo[4] = {{uv0.x, uv0.y}, {uv1.x, uv1.y}, {uv2.x, uv2.y}, {uv3.x, uv3.y}};
            const float2v uhi[4] = {{uv0.z, uv0.w}, {uv1.z, uv1.w}, {uv2.z, uv2.w}, {uv3.z, uv3.w}};
            #pragma unroll
            for (int i = 0; i < 4; ++i) {       // k+i, sequential -> exact chain order
                #pragma unroll
                for (int r = 0; r < 4; ++r) {
                    float2v vd = {vs[r][i], vs[r][i]};
                    PKFMA(accL[r], vd, wlo[i]);
                    PKFMA(accH[r], vd, whi[i]);
                    PKFMA(accWL[r], vd, ulo[i]);
                    PKFMA(accWH[r], vd, uhi[i]);
                }
            }
        }
        const float4 bv4 = *(const float4*)(bv + c0);
        const float4 b24 = *(const float4*)(bvW + c0);
        const float4 wp4 = *(const float4*)(wp2f + c0);
        #pragma unroll
        for (int r = 0; r < 4; ++r) {
            int row = r0 + 4 * wvid + r;
            float4 vd4;
            vd4.x = accL[r].x + bv4.x;
            vd4.y = accL[r].y + bv4.y;
            vd4.z = accH[r].x + bv4.z;
            vd4.w = accH[r].y + bv4.w;
            *(float4*)(v2d + (size_t)row * C_ + c0) = vd4;
            uint_t us0 = __half_as_ushort(__float2half(accWL[r].x + b24.x));
            uint_t us1 = __half_as_ushort(__float2half(accWL[r].y + b24.y));
            uint_t us2 = __half_as_ushort(__float2half(accWH[r].x + b24.z));
            uint_t us3 = __half_as_ushort(__float2half(accWH[r].y + b24.w));
            uint2 pk;
            pk.x = us0 | (us1 << 16);
            pk.y = us2 | (us3 << 16);
            *(uint2*)(VW + (size_t)row * C_ + c0) = pk;
            // S32 partial: 4 in-lane + 8-lane tree (head = l>>3); gap test absorbs reorder noise
            float p = ((vd4.x * wp4.x + vd4.y * wp4.y) + vd4.z * wp4.z) + vd4.w * wp4.w;
            p += __shfl_down(p, 4, 8);
            p += __shfl_down(p, 2, 8);
            p += __shfl_down(p, 1, 8);
            if ((l & 7) == 0) {
                int h = l >> 3;
                int pix = row - (row / NPIX) * NPIX;
                S32Q[((size_t)row * HEADS + h) * 4 + 0] = p;
                if (pix >= 1)
                    S32Q[((size_t)(row - 1) * HEADS + h) * 4 + 1] = p;
                if (pix >= WV)
                    S32Q[((size_t)(row - WV) * HEADS + h) * 4 + 2] = p;
                if (pix >= WV + 1)
                    S32Q[((size_t)(row - WV - 1) * HEADS + h) * 4 + 3] = p;
            }
        }
    } else {
        // ===== query part: 16 rows/block, two independent 128-thread halves (R12/R13-verified) =====
        int qb = blk - NVBLK2;
        int half = t >> 7, tt = t & 127;
        int rb = qb * 16 + half * 8;
        float (*qs)[C_] = (float (*)[C_])sbuf;
        float (*lg)[32] = (float (*)[32])(sbuf + 16 * C_);
        #pragma unroll
        for (int i = 0; i < 16; ++i) {
            int idx = tt + i * 128;
            int rr = idx >> 8, cc = idx & 255;
            qs[half * 8 + rr][cc] = query[(size_t)(rb + rr) * C_ + cc];
        }
        __syncthreads();
        if (tt < 64) {
            float acc[8] = {0.f, 0.f, 0.f, 0.f, 0.f, 0.f, 0.f, 0.f};
            for (int k4 = 0; k4 < C_ / 4; ++k4) {
                int k = k4 * 4;
                float w0 = Wo[(k + 0) * 64 + tt], w1 = Wo[(k + 1) * 64 + tt];
                float w2 = Wo[(k + 2) * 64 + tt], w3 = Wo[(k + 3) * 64 + tt];
                #pragma unroll
                for (int r = 0; r < 8; ++r) {
                    const float4 qv = *(reinterpret_cast<const float4*>(qs[half * 8 + r]) + k4);
                    acc[r] = __builtin_fmaf(qv.x, w0, acc[r]);
                    acc[r] = __builtin_fmaf(qv.y, w1, acc[r]);
                    acc[r] = __builtin_fmaf(qv.z, w2, acc[r]);
                    acc[r] = __builtin_fmaf(qv.w, w3, acc[r]);
                }
            }
            float b = bo[tt];
            float nrm = (tt & 1) ? 23.0f : 46.0f;
            #pragma unroll
            for (int r = 0; r < 8; ++r) offn[(size_t)(rb + r) * 64 + tt] = (acc[r] + b) / nrm;
        } else {
            // Wa wave, lane-split: lanes 0-31 rows 0-3, lanes 32-63 rows 4-7
            int u = tt - 64;
            int j = u & 31;
            int rbase = (u >> 5) * 4;
            float acc[4] = {0.f, 0.f, 0.f, 0.f};
            for (int k4 = 0; k4 < C_ / 4; ++k4) {
                int k = k4 * 4;
                float w0 = Wa[(k + 0) * 32 + j], w1 = Wa[(k + 1) * 32 + j];
                float w2 = Wa[(k + 2) * 32 + j], w3 = Wa[(k + 3) * 32 + j];
                #pragma unroll
                for (int r = 0; r < 4; ++r) {
                    const float4 qv = *(reinterpret_cast<const float4*>(qs[half * 8 + rbase + r]) + k4);
                    acc[r] = __builtin_fmaf(qv.x, w0, acc[r]);
                    acc[r] = __builtin_fmaf(qv.y, w1, acc[r]);
                    acc[r] = __builtin_fmaf(qv.z, w2, acc[r]);
                    acc[r] = __builtin_fmaf(qv.w, w3, acc[r]);
                }
            }
            float b = ba[j];
            #pragma unroll
            for (int r = 0; r < 4; ++r) lg[half * 8 + rbase + r][j] = acc[r] + b;
        }
        __syncthreads();
        if (tt < 64) {
            int r = tt >> 3, h = tt & 7;
            int lr = half * 8 + r;
            float v0 = lg[lr][h * 4 + 0], v1 = lg[lr][h * 4 + 1];
            float v2 = lg[lr][h * 4 + 2], v3 = lg[lr][h * 4 + 3];
            float m = fmaxf(fmaxf(fmaxf(v0, v1), v2), v3);
            float e0 = expf(v0 - m), e1 = expf(v1 - m), e2 = expf(v2 - m), e3 = expf(v3 - m);
            float s = ((e0 + e1) + e2) + e3;
            attn[(size_t)(rb + r) * 32 + h * 4 + 0] = e0 / s;
            attn[(size_t)(rb + r) * 32 + h * 4 + 1] = e1 / s;
            attn[(size_t)(rb + r) * 32 + h * 4 + 2] = e2 / s;
            attn[(size_t)(rb + r) * 32 + h * 4 + 3] = e3 / s;
        }
    }
}

// ---------------- fused: f32 gap-tested logits (quad S32Q, 1x16B load) + hfma2 sampling + epilogue prefetch ----------------
__global__ void __launch_bounds__(256) fused_kernel(
        const ushort_t* __restrict__ VW, const float* __restrict__ offn,
        const float* __restrict__ attn, const float* __restrict__ grd_col,
        const float* __restrict__ grd_row, const float* __restrict__ S32Q,
        const float* __restrict__ query, const float* __restrict__ bout,
        float* __restrict__ out, float* __restrict__ amax_out,
        int* __restrict__ cnt, int* __restrict__ list) {
    int bid = blockIdx.x;
    int row = ((bid & 7) << 12) | (bid >> 3);   // XCD-bijective: batch <-> XCD affinity
    int b = row >> 12;
    int q = row & (NQ - 1);
    int t = threadIdx.x;
    __shared__ __align__(16) int     g_ip[256][4];
    __shared__ __align__(16) __half2 g_wh[256][4];   // duplicated half2 per corner weight
    __shared__ __align__(16) float red[NV][C_];
    __shared__ float logits_sh[NV];
    __shared__ float wf_sh[NV];

    // epilogue prefetch: issue early so L2/HBM latency hides under phases A/B
    float q_pre = query[(size_t)row * C_ + t];
    float b_pre = bout[t];

    // ---- phase A (f32): t = v*32 + (h*4+p)
    {
        int v = t >> 5, r = t & 31, h = r >> 2;
        const float2 off2 = ((const float2*)(offn + (size_t)row * 64))[r];
        float at = attn[(size_t)row * 32 + r];
        float refx = grd_col[q * NV + v];
        float refy = grd_row[q * NV + v];
        float lx = refx + off2.x;
        float ly = refy + off2.y;
        float x = lx * 46.0f - 0.5f;
        float y = ly * 23.0f - 0.5f;
        float x0f = floorf(x), y0f = floorf(y);
        float wx1 = x - x0f, wy1 = y - y0f;
        float wx0 = 1.0f - wx1, wy0 = 1.0f - wy1;
        int xi = (int)x0f, yi = (int)y0f;
        bool vx0 = (x0f >= 0.0f) && (x0f < 46.0f);
        bool vx1 = (x0f + 1.0f >= 0.0f) && (x0f + 1.0f < 46.0f);
        bool vy0 = (y0f >= 0.0f) && (y0f < 23.0f);
        bool vy1 = (y0f + 1.0f >= 0.0f) && (y0f + 1.0f < 23.0f);
        int xc0 = min(max(xi, 0), WV - 1), xc1 = min(max(xi + 1, 0), WV - 1);
        int yc0 = min(max(yi, 0), HV - 1), yc1 = min(max(yi + 1, 0), HV - 1);
        float w00 = (vx0 && vy0) ? wx0 * wy0 : 0.0f;
        float w10 = (vx1 && vy0) ? wx1 * wy0 : 0.0f;
        float w01 = (vx0 && vy1) ? wx0 * wy1 : 0.0f;
        float w11 = (vx1 && vy1) ? wx1 * wy1 : 0.0f;
        int ip00 = yc0 * WV + xc0, ip10 = yc0 * WV + xc1;
        int ip01 = yc1 * WV + xc0, ip11 = yc1 * WV + xc1;

        g_ip[t][0] = ip00 * (C_ * 2); g_ip[t][1] = ip10 * (C_ * 2);   // byte offsets
        g_ip[t][2] = ip01 * (C_ * 2); g_ip[t][3] = ip11 * (C_ * 2);
        __half hw0 = __float2half(w00 * at);
        __half hw1 = __float2half(w10 * at);
        __half hw2 = __float2half(w01 * at);
        __half hw3 = __float2half(w11 * at);
        g_wh[t][0] = __halves2half2(hw0, hw0);
        g_wh[t][1] = __halves2half2(hw1, hw1);
        g_wh[t][2] = __halves2half2(hw2, hw2);
        g_wh[t][3] = __halves2half2(hw3, hw3);

        // quad S32 load: slot[ip] = (S[ip], S[ip+1], S[ip+WV], S[ip+WV+1])
        const float4* Sb = (const float4*)S32Q + (size_t)b * NPIX * HEADS;
        float4 sq = Sb[ip00 * HEADS + h];
        float s10 = (ip10 == ip00) ? sq.x : sq.y;
        float s01 = (ip01 == ip00) ? sq.x : sq.z;
        float hi0 = (ip01 == ip00) ? sq.y : sq.w;
        float s11 = (ip11 == ip01) ? s01 : hi0;
        float samp = w00 * sq.x + w10 * s10 + w01 * s01 + w11 * s11;
        float contrib = at * samp;
        #pragma unroll
        for (int s2 = 16; s2; s2 >>= 1) contrib += __shfl_down(contrib, s2, 32);
        if (r == 0) logits_sh[v] = contrib;
    }
    __syncthreads();                                   // barrier 1 (A -> B)

    // ---- lanes 0..7 (f32): argmax + gap test + softmax weights
    if (t < 8) {
        float m = logits_sh[0]; int am = 0;
        #pragma unroll
        for (int v2 = 1; v2 < NV; ++v2) {
            float lv = logits_sh[v2];
            if (lv > m) { m = lv; am = v2; }
        }
        float e = expf(logits_sh[t] - m);
        float ssum = e;
        ssum += __shfl_xor(ssum, 1, 8);
        ssum += __shfl_xor(ssum, 2, 8);
        ssum += __shfl_xor(ssum, 4, 8);
        wf_sh[t] = e / ssum;
        if (t == 0) {
            amax_out[row] = (float)am;
            float m2 = -1e30f;
            #pragma unroll
            for (int v2 = 0; v2 < NV; ++v2) {
                float lv = logits_sh[v2];
                if (v2 != am && lv > m2) m2 = lv;
            }
            float thr = 1e-4f * fmaxf(1.0f, fabsf(m));
            if ((m - m2) < thr) {
                int idx = atomicAdd(cnt, 1);
                list[idx] = row;
            }
        }
    }

    // ---- phase B: 8 groups x 32 threads; group g = v; 8 channels/thread; packed f16 FMA
    {
        int g = t >> 5, lt = t & 31;
        int c0 = lt * 8;
        int c2 = c0 * 2;               // channel byte offset
        int hb = lt >> 2;
        const char* vb = (const char*)(VW + (size_t)b * NPIX * C_);
        __half2 h01 = __float2half2_rn(0.f);
        __half2 h23 = h01, h45 = h01, h67 = h01;
        #pragma unroll
        for (int pp = 0; pp < 2; ++pp) {
            int e0 = g * 32 + hb * 4 + pp * 2;         // entry (v=g, h=hb, p=pp*2); +1 -> p+1
            const int4   ipA = *reinterpret_cast<const int4*>(g_ip[e0]);
            const uint4  whA = *reinterpret_cast<const uint4*>(g_wh[e0]);
            const int4   ipB = *reinterpret_cast<const int4*>(g_ip[e0 + 1]);
            const uint4  whB = *reinterpret_cast<const uint4*>(g_wh[e0 + 1]);
            const uint4 uA0 = *reinterpret_cast<const uint4*>(vb + (ipA.x + c2));
            const uint4 uA1 = *reinterpret_cast<const uint4*>(vb + (ipA.y + c2));
            const uint4 uA2 = *reinterpret_cast<const uint4*>(vb + (ipA.z + c2));
            const uint4 uA3 = *reinterpret_cast<const uint4*>(vb + (ipA.w + c2));
            const uint4 uB0 = *reinterpret_cast<const uint4*>(vb + (ipB.x + c2));
            const uint4 uB1 = *reinterpret_cast<const uint4*>(vb + (ipB.y + c2));
            const uint4 uB2 = *reinterpret_cast<const uint4*>(vb + (ipB.z + c2));
            const uint4 uB3 = *reinterpret_cast<const uint4*>(vb + (ipB.w + c2));
            #define CORNER(WHU, U) { \
                const __half2 wh = *reinterpret_cast<const __half2*>(&WHU); \
                h01 = __hfma2(wh, *reinterpret_cast<const __half2*>(&U.x), h01); \
                h23 = __hfma2(wh, *reinterpret_cast<const __half2*>(&U.y), h23); \
                h45 = __hfma2(wh, *reinterpret_cast<const __half2*>(&U.z), h45); \
                h67 = __hfma2(wh, *reinterpret_cast<const __half2*>(&U.w), h67); }
            CORNER(whA.x, uA0)
            CORNER(whA.y, uA1)
            CORNER(whA.z, uA2)
            CORNER(whA.w, uA3)
            CORNER(whB.x, uB0)
            CORNER(whB.y, uB1)
            CORNER(whB.z, uB2)
            CORNER(whB.w, uB3)
            #undef CORNER
        }
        float a0 = __low2float(h01), a1 = __high2float(h01);
        float a2 = __low2float(h23), a3 = __high2float(h23);
        float a4 = __low2float(h45), a5 = __high2float(h45);
        float a6 = __low2float(h67), a7 = __high2float(h67);
        float4 s0v = {a0, a1, a2, a3}, s1v = {a4, a5, a6, a7};
        *reinterpret_cast<float4*>(&red[g][c0])     = s0v;
        *reinterpret_cast<float4*>(&red[g][c0 + 4]) = s1v;
    }
    __syncthreads();                                   // barrier 2 (B -> epilogue)
    float O = 0.f;
    #pragma unroll
    for (int g8 = 0; g8 < NV; ++g8) O = fmaf(wf_sh[g8], red[g8][t], O);
    out[(size_t)row * C_ + t] = O + b_pre + 2.0f * q_pre;
}

// ---------------- exact replication (compacted: grid-stride over flagged list) ----------------
__global__ void __launch_bounds__(256) exact_kernel(
        const float* __restrict__ v2d, const float* __restrict__ offn,
        const float* __restrict__ attn, const float* __restrict__ grd_col,
        const float* __restrict__ grd_row, const float* __restrict__ Wout,
        const float* __restrict__ bout, const float* __restrict__ Wp,
        const float* __restrict__ bp, const float* __restrict__ query,
        const int* __restrict__ cnt, const int* __restrict__ list,
        float* __restrict__ amax_out) {
#pragma clang fp contract(off)
    int n = *cnt;
    int t = threadIdx.x;
    int h = t >> 5;
    __shared__ float s_off[64];
    __shared__ float s_attn[32];
    __shared__ float wp_lds[C_];
    __shared__ float out_l[NV][C_ + 1];
    __shared__ float bevs_l[NV][C_ + 1];
    __shared__ float lgs[NV];
    wp_lds[t] = Wp[t];

    for (int i = blockIdx.x; i < n; i += gridDim.x) {
        int row = list[i];
        int b = row >> 12;
        int q = row & (NQ - 1);
        if (t < 64)      s_off[t]       = offn[(size_t)row * 64 + t];
        else if (t < 96) s_attn[t - 64] = attn[(size_t)row * 32 + (t - 64)];
        __syncthreads();

        const float* vb = v2d + (size_t)b * NPIX * C_;
        #pragma unroll
        for (int v = 0; v < NV; ++v) {
            float refx = grd_col[q * NV + v];
            float refy = grd_row[q * NV + v];
            float acc = 0.0f;
            #pragma unroll
            for (int p = 0; p < PTS; ++p) {
                float lx = refx + s_off[h * 8 + p * 2 + 0];
                float ly = refy + s_off[h * 8 + p * 2 + 1];
                float x = lx * 46.0f - 0.5f;
                float y = ly * 23.0f - 0.5f;
                float x0f = floorf(x), y0f = floorf(y);
                float wx1 = x - x0f, wy1 = y - y0f;
                float wx0 = 1.0f - wx1, wy0 = 1.0f - wy1;
                int xi = (int)x0f, yi = (int)y0f;
                bool vx0 = (x0f >= 0.0f) && (x0f < 46.0f);
                bool vx1 = (x0f + 1.0f >= 0.0f) && (x0f + 1.0f < 46.0f);
                bool vy0 = (y0f >= 0.0f) && (y0f < 23.0f);
                bool vy1 = (y0f + 1.0f >= 0.0f) && (y0f + 1.0f < 23.0f);
                int xc0 = min(max(xi, 0), WV - 1), xc1 = min(max(xi + 1, 0), WV - 1);
                int yc0 = min(max(yi, 0), HV - 1), yc1 = min(max(yi + 1, 0), HV - 1);
                float g00 = (vx0 && vy0) ? vb[(yc0 * WV + xc0) * C_ + t] : 0.0f;
                float g10 = (vx1 && vy0) ? vb[(yc0 * WV + xc1) * C_ + t] : 0.0f;
                float g01 = (vx0 && vy1) ? vb[(yc1 * WV + xc0) * C_ + t] : 0.0f;
                float g11 = (vx1 && vy1) ? vb[(yc1 * WV + xc1) * C_ + t] : 0.0f;
                float t00 = g00 * (wx0 * wy0);
                float t10 = g10 * (wx1 * wy0);
                float t01 = g01 * (wx0 * wy1);
                float t11 = g11 * (wx1 * wy1);
                float samp = ((t00 + t10) + t01) + t11;
                float pr = s_attn[h * 4 + p] * samp;
                acc = acc + pr;
            }
            out_l[v][t] = acc;
        }
        __syncthreads();

        float bacc[NV];
        #pragma unroll
        for (int v = 0; v < NV; ++v) bacc[v] = 0.f;
        for (int i2 = 0; i2 < C_; ++i2) {
            float w_it = Wout[i2 * C_ + t];
            #pragma unroll
            for (int v = 0; v < NV; ++v) bacc[v] = __builtin_fmaf(out_l[v][i2], w_it, bacc[v]);
        }
        float bo_t = bout[t];
        float qv = query[(size_t)row * C_ + t];
        #pragma unroll
        for (int v = 0; v < NV; ++v) bevs_l[v][t] = (bacc[v] + bo_t) + qv;
        __syncthreads();

        if (t < NV) {
            float lv = 0.f;
            for (int c = 0; c < C_; ++c) lv = __builtin_fmaf(bevs_l[t][c], wp_lds[c], lv);
            lgs[t] = lv + bp[0];
        }
        __syncthreads();

        if (t == 0) {
            float l[NV];
            #pragma unroll
            for (int v = 0; v < NV; ++v) l[v] = lgs[v];
            float m = l[0];
            #pragma unroll
            for (int v = 1; v < NV; ++v) m = fmaxf(m, l[v]);
            float e[NV];
            #pragma unroll
            for (int v = 0; v < NV; ++v) e[v] = expf(l[v] - m);
            float s = ((e[0] + e[1]) + (e[2] + e[3])) + ((e[4] + e[5]) + (e[6] + e[7]));
            float w[NV];
            #pragma unroll
            for (int v = 0; v < NV; ++v) w[v] = e[v] / s;
            int am = 0; float wm = w[0];
            #pragma unroll
            for (int v = 1; v < NV; ++v) { if (w[v] > wm) { wm = w[v]; am = v; } }
            amax_out[row] = (float)am;
        }
        __syncthreads();
    }
}

extern "C" void kernel_launch(void* const* d_in, const int* in_sizes, int n_in,
                              void* d_out, int out_size, void* d_ws, size_t ws_size,
                              hipStream_t stream) {
    const float* query   = (const float*)d_in[0];
    const float* value   = (const float*)d_in[1];
    const float* grd_col = (const float*)d_in[2];
    const float* grd_row = (const float*)d_in[3];
    const float* Wv      = (const float*)d_in[4];
    const float* bv      = (const float*)d_in[5];
    const float* Wo      = (const float*)d_in[6];
    const float* bo      = (const float*)d_in[7];
    const float* Wa      = (const float*)d_in[8];
    const float* ba      = (const float*)d_in[9];
    const float* Wout    = (const float*)d_in[10];
    const float* bout    = (const float*)d_in[11];
    const float* Wp      = (const float*)d_in[12];
    const float* bp      = (const float*)d_in[13];

    float* out  = (float*)d_out;
    float* ws   = (float*)d_ws;
    float* offn = ws;                                        // 32768*64 f32
    float* attn = offn + (size_t)NROW * 64;                  // 32768*32 f32
    float* v2d  = attn + (size_t)NROW * 32;                  // 8464*256 f32
    float* wp2f = v2d + (size_t)BS * NPIX * C_;              // 256 f32
    float* S32Q = wp2f + C_;                                 // 8464*8 float4 = 270848 f32
    int* cnt    = (int*)(S32Q + (size_t)BS * NPIX * HEADS * 4); // 1 int (padded to 4)
    int* list   = cnt + 4;                                   // 32768 int
    ushort_t* VW = (ushort_t*)(list + NROW);                 // 8464*256 fp16
    float* WvWout = (float*)(VW + (size_t)BS * NPIX * C_);   // 256*256 f32
    float* bvW    = WvWout + C_ * C_;                        // 256 f32
    float* amax = out + (size_t)NROW * C_;

    prep_kernel<<<65, 256, 0, stream>>>(Wout, Wp, Wv, bv, WvWout, wp2f, bvW, cnt);
    proj_kernel<<<NVBLK2 + NQBLK, 256, 0, stream>>>(value, Wv, bv, WvWout, bvW, wp2f,
                                                    query, Wo, bo, Wa, ba,
                                                    v2d, VW, S32Q, offn, attn);
    fused_kernel<<<NROW, 256, 0, stream>>>(VW, offn, attn, grd_col, grd_row, S32Q,
                                           query, bout, out, amax, cnt, list);
    exact_kernel<<<512, 256, 0, stream>>>(v2d, offn, attn, grd_col, grd_row,
                                          Wout, bout, Wp, bp, query, cnt, list, amax);
}

// Round 15
// 208.033 us; speedup vs baseline: 1.0300x; 1.0300x over previous
//
#include <hip/hip_runtime.h>
#include <hip/hip_fp16.h>

#define NV 8
#define NQ 4096
#define C_ 256
#define HEADS 8
#define PTS 4
#define HV 23
#define WV 46
#define NPIX (HV*WV)       // 1058
#define BS 8
#define NROW (BS*NQ)       // 32768
#define NVBLK2 ((BS*NPIX)/16) // 529 value blocks (16 rows each)
#define NQBLK (NROW/16)       // 2048 query blocks

typedef unsigned short ushort_t;
typedef unsigned int uint_t;
typedef float float2v __attribute__((ext_vector_type(2)));

// packed f32 FMA: ACC(pair) += V(pair) * W(pair, both halves equal) -- IEEE-identical per lane
#define PKFMA(ACC, V, W) asm("v_pk_fma_f32 %0, %1, %2, %0" : "+v"(ACC) : "v"(V), "v"(W))

// ---------------- prep (65 blocks): 0..63 WvWout = Wv@Wout; 64: wp2f = Wout@Wp, bvW = bv@Wout, cnt=0 ----------------
__global__ void prep_kernel(const float* __restrict__ Wout, const float* __restrict__ Wp,
                            const float* __restrict__ Wv, const float* __restrict__ bv,
                            float* __restrict__ WvWout, float* __restrict__ wp2f,
                            float* __restrict__ bvW, int* __restrict__ cnt) {
    int blk = blockIdx.x;
    int t = threadIdx.x;
    __shared__ float rows[4][C_];
    if (blk < 64) {
        int r0 = blk * 4;
        #pragma unroll
        for (int r = 0; r < 4; ++r) rows[r][t] = Wv[(r0 + r) * C_ + t];
        __syncthreads();
        float acc[4] = {0.f, 0.f, 0.f, 0.f};
        for (int k = 0; k < C_; ++k) {
            float w = Wout[k * C_ + t];
            acc[0] = fmaf(rows[0][k], w, acc[0]);
            acc[1] = fmaf(rows[1][k], w, acc[1]);
            acc[2] = fmaf(rows[2][k], w, acc[2]);
            acc[3] = fmaf(rows[3][k], w, acc[3]);
        }
        #pragma unroll
        for (int r = 0; r < 4; ++r) WvWout[(r0 + r) * C_ + t] = acc[r];
    } else {
        if (t == 0) *cnt = 0;
        float a = 0.f;
        for (int c = 0; c < C_; ++c) a = fmaf(Wout[t * C_ + c], Wp[c], a);
        wp2f[t] = a;
        float fb = 0.f;
        for (int d = 0; d < C_; ++d) fb = fmaf(bv[d], Wout[d * C_ + t], fb);
        bvW[t] = fb;
    }
}

// ---------------- proj: value blocks (R13 pair-interleaved pk-FMA) + quad S32Q; query blocks (NEW: pk-FMA too) ----------------
// Both parts stage rows pair-interleaved: sbuf[(row>>1)*512 + col*2 + (row&1)]. One b128 read
// yields {rA[k],rB[k],rA[k+1],rB[k+1]} = two pk operands. Per-(row,col) chains keep exact
// sequential-k order -> v2d/VW/S32Q/offn/attn bit-identical to R13/R12.
__global__ void proj_kernel(const float* __restrict__ value, const float* __restrict__ Wv,
                            const float* __restrict__ bv, const float* __restrict__ WvWout,
                            const float* __restrict__ bvW, const float* __restrict__ wp2f,
                            const float* __restrict__ query,
                            const float* __restrict__ Wo, const float* __restrict__ bo,
                            const float* __restrict__ Wa, const float* __restrict__ ba,
                            float* __restrict__ v2d, ushort_t* __restrict__ VW,
                            float* __restrict__ S32Q, float* __restrict__ offn,
                            float* __restrict__ attn) {
#pragma clang fp contract(off)
    __shared__ __align__(16) float sbuf[16 * C_ + 16 * 32];
    int blk = blockIdx.x;
    int t = threadIdx.x;
    if (blk < NVBLK2) {
        // ===== value part (R13-verified) =====
        int r0 = blk * 16;
        #pragma unroll
        for (int i = 0; i < 16; ++i) {
            int idx = t + i * 256;
            int row = idx >> 8, col = idx & 255;
            sbuf[((row >> 1) << 9) + (col << 1) + (row & 1)] = value[(size_t)r0 * C_ + idx];
        }
        __syncthreads();
        float2v acc2[8], accW2[8];
        #pragma unroll
        for (int p = 0; p < 8; ++p) { acc2[p] = (float2v){0.f, 0.f}; accW2[p] = (float2v){0.f, 0.f}; }
        const float4* ldsq = (const float4*)sbuf;
        for (int k4 = 0; k4 < C_ / 4; ++k4) {
            int k = k4 * 4;
            float w0 = Wv[(k + 0) * C_ + t], w1 = Wv[(k + 1) * C_ + t];
            float w2 = Wv[(k + 2) * C_ + t], w3 = Wv[(k + 3) * C_ + t];
            float u0 = WvWout[(k + 0) * C_ + t], u1 = WvWout[(k + 1) * C_ + t];
            float u2 = WvWout[(k + 2) * C_ + t], u3 = WvWout[(k + 3) * C_ + t];
            float2v w20 = {w0, w0}, w21 = {w1, w1}, w22 = {w2, w2}, w23 = {w3, w3};
            float2v u20 = {u0, u0}, u21 = {u1, u1}, u22 = {u2, u2}, u23 = {u3, u3};
            #pragma unroll
            for (int p = 0; p < 8; ++p) {
                const float4 qa = ldsq[p * 128 + 2 * k4];       // {vA[k],vB[k],vA[k+1],vB[k+1]}
                const float4 qb = ldsq[p * 128 + 2 * k4 + 1];   // k+2, k+3
                float2v v0 = {qa.x, qa.y}, v1 = {qa.z, qa.w};
                float2v v2 = {qb.x, qb.y}, v3 = {qb.z, qb.w};
                PKFMA(acc2[p], v0, w20);    // exact: sequential k order per row chain
                PKFMA(acc2[p], v1, w21);
                PKFMA(acc2[p], v2, w22);
                PKFMA(acc2[p], v3, w23);
                PKFMA(accW2[p], v0, u20);
                PKFMA(accW2[p], v1, u21);
                PKFMA(accW2[p], v2, u22);
                PKFMA(accW2[p], v3, u23);
            }
        }
        float b = bv[t];
        float b2 = bvW[t];
        float wpt = wp2f[t];
        #pragma unroll
        for (int r = 0; r < 16; ++r) {
            float a  = (r & 1) ? acc2[r >> 1].y  : acc2[r >> 1].x;
            float aw = (r & 1) ? accW2[r >> 1].y : accW2[r >> 1].x;
            float vd = a + b;
            v2d[(size_t)(r0 + r) * C_ + t] = vd;
            VW[(size_t)(r0 + r) * C_ + t] = __half_as_ushort(__float2half(aw + b2));
            // S32Q scatter: slot[row].x, slot[row-1].y, slot[row-WV].z, slot[row-WV-1].w
            float p = vd * wpt;
            p += __shfl_down(p, 16, 32);
            p += __shfl_down(p, 8, 32);
            p += __shfl_down(p, 4, 32);
            p += __shfl_down(p, 2, 32);
            p += __shfl_down(p, 1, 32);
            if ((t & 31) == 0) {
                int row = r0 + r;
                int h = t >> 5;
                int pix = row - (row / NPIX) * NPIX;
                S32Q[((size_t)row * HEADS + h) * 4 + 0] = p;
                if (pix >= 1)
                    S32Q[((size_t)(row - 1) * HEADS + h) * 4 + 1] = p;
                if (pix >= WV)
                    S32Q[((size_t)(row - WV) * HEADS + h) * 4 + 2] = p;
                if (pix >= WV + 1)
                    S32Q[((size_t)(row - WV - 1) * HEADS + h) * 4 + 3] = p;
            }
        }
    } else {
        // ===== query part: pair-interleaved staging + pk-FMA (NEW) =====
        int qb = blk - NVBLK2;
        int half = t >> 7, tt = t & 127;
        int rb = qb * 16 + half * 8;
        float (*lg)[32] = (float (*)[32])(sbuf + 16 * C_);
        #pragma unroll
        for (int i = 0; i < 16; ++i) {
            int idx = tt + i * 128;
            int rr = idx >> 8, cc = idx & 255;
            int grow = half * 8 + rr;
            sbuf[((grow >> 1) << 9) + (cc << 1) + (grow & 1)] = query[(size_t)(rb + rr) * C_ + cc];
        }
        __syncthreads();
        const float4* ldsq = (const float4*)sbuf;
        if (tt < 64) {
            // Wo wave: col = tt; pairs half*4 .. half*4+3 (rows half*8 .. +7)
            float2v acc2[4];
            #pragma unroll
            for (int p = 0; p < 4; ++p) acc2[p] = (float2v){0.f, 0.f};
            for (int k4 = 0; k4 < C_ / 4; ++k4) {
                int k = k4 * 4;
                float w0 = Wo[(k + 0) * 64 + tt], w1 = Wo[(k + 1) * 64 + tt];
                float w2 = Wo[(k + 2) * 64 + tt], w3 = Wo[(k + 3) * 64 + tt];
                float2v w20 = {w0, w0}, w21 = {w1, w1}, w22 = {w2, w2}, w23 = {w3, w3};
                #pragma unroll
                for (int p = 0; p < 4; ++p) {
                    int pg = half * 4 + p;
                    const float4 qa = ldsq[pg * 128 + 2 * k4];
                    const float4 qb2 = ldsq[pg * 128 + 2 * k4 + 1];
                    float2v v0 = {qa.x, qa.y}, v1 = {qa.z, qa.w};
                    float2v v2 = {qb2.x, qb2.y}, v3 = {qb2.z, qb2.w};
                    PKFMA(acc2[p], v0, w20);    // exact sequential-k per row chain
                    PKFMA(acc2[p], v1, w21);
                    PKFMA(acc2[p], v2, w22);
                    PKFMA(acc2[p], v3, w23);
                }
            }
            float b = bo[tt];
            float nrm = (tt & 1) ? 23.0f : 46.0f;
            #pragma unroll
            for (int p = 0; p < 4; ++p) {
                offn[(size_t)(rb + 2 * p) * 64 + tt]     = (acc2[p].x + b) / nrm;
                offn[(size_t)(rb + 2 * p + 1) * 64 + tt] = (acc2[p].y + b) / nrm;
            }
        } else {
            // Wa wave, lane-split: u in 0..63; j = u&31; lanes<32 rows 0-3, lanes>=32 rows 4-7
            int u = tt - 64;
            int j = u & 31;
            int rbase = (u >> 5) * 4;                  // 0 or 4 (local to half)
            int pb = half * 4 + (rbase >> 1);          // global pair base (2 pairs)
            float2v acc2[2];
            acc2[0] = (float2v){0.f, 0.f}; acc2[1] = (float2v){0.f, 0.f};
            for (int k4 = 0; k4 < C_ / 4; ++k4) {
                int k = k4 * 4;
                float w0 = Wa[(k + 0) * 32 + j], w1 = Wa[(k + 1) * 32 + j];
                float w2 = Wa[(k + 2) * 32 + j], w3 = Wa[(k + 3) * 32 + j];
                float2v w20 = {w0, w0}, w21 = {w1, w1}, w22 = {w2, w2}, w23 = {w3, w3};
                #pragma unroll
                for (int p = 0; p < 2; ++p) {
                    const float4 qa = ldsq[(pb + p) * 128 + 2 * k4];
                    const float4 qb2 = ldsq[(pb + p) * 128 + 2 * k4 + 1];
                    float2v v0 = {qa.x, qa.y}, v1 = {qa.z, qa.w};
                    float2v v2 = {qb2.x, qb2.y}, v3 = {qb2.z, qb2.w};
                    PKFMA(acc2[p], v0, w20);
                    PKFMA(acc2[p], v1, w21);
                    PKFMA(acc2[p], v2, w22);
                    PKFMA(acc2[p], v3, w23);
                }
            }
            float b = ba[j];
            #pragma unroll
            for (int p = 0; p < 2; ++p) {
                lg[half * 8 + rbase + 2 * p][j]     = acc2[p].x + b;
                lg[half * 8 + rbase + 2 * p + 1][j] = acc2[p].y + b;
            }
        }
        __syncthreads();
        if (tt < 64) {
            int r = tt >> 3, h = tt & 7;
            int lr = half * 8 + r;
            float v0 = lg[lr][h * 4 + 0], v1 = lg[lr][h * 4 + 1];
            float v2 = lg[lr][h * 4 + 2], v3 = lg[lr][h * 4 + 3];
            float m = fmaxf(fmaxf(fmaxf(v0, v1), v2), v3);
            float e0 = expf(v0 - m), e1 = expf(v1 - m), e2 = expf(v2 - m), e3 = expf(v3 - m);
            float s = ((e0 + e1) + e2) + e3;
            attn[(size_t)(rb + r) * 32 + h * 4 + 0] = e0 / s;
            attn[(size_t)(rb + r) * 32 + h * 4 + 1] = e1 / s;
            attn[(size_t)(rb + r) * 32 + h * 4 + 2] = e2 / s;
            attn[(size_t)(rb + r) * 32 + h * 4 + 3] = e3 / s;
        }
    }
}

// ---------------- fused: f32 gap-tested logits (quad S32Q, 1x16B load) + hfma2 sampling + epilogue prefetch ----------------
__global__ void __launch_bounds__(256) fused_kernel(
        const ushort_t* __restrict__ VW, const float* __restrict__ offn,
        const float* __restrict__ attn, const float* __restrict__ grd_col,
        const float* __restrict__ grd_row, const float* __restrict__ S32Q,
        const float* __restrict__ query, const float* __restrict__ bout,
        float* __restrict__ out, float* __restrict__ amax_out,
        int* __restrict__ cnt, int* __restrict__ list) {
    int bid = blockIdx.x;
    int row = ((bid & 7) << 12) | (bid >> 3);   // XCD-bijective: batch <-> XCD affinity
    int b = row >> 12;
    int q = row & (NQ - 1);
    int t = threadIdx.x;
    __shared__ __align__(16) int     g_ip[256][4];
    __shared__ __align__(16) __half2 g_wh[256][4];   // duplicated half2 per corner weight
    __shared__ __align__(16) float red[NV][C_];
    __shared__ float logits_sh[NV];
    __shared__ float wf_sh[NV];

    // epilogue prefetch: issue early so L2/HBM latency hides under phases A/B
    float q_pre = query[(size_t)row * C_ + t];
    float b_pre = bout[t];

    // ---- phase A (f32): t = v*32 + (h*4+p)
    {
        int v = t >> 5, r = t & 31, h = r >> 2;
        const float2 off2 = ((const float2*)(offn + (size_t)row * 64))[r];
        float at = attn[(size_t)row * 32 + r];
        float refx = grd_col[q * NV + v];
        float refy = grd_row[q * NV + v];
        float lx = refx + off2.x;
        float ly = refy + off2.y;
        float x = lx * 46.0f - 0.5f;
        float y = ly * 23.0f - 0.5f;
        float x0f = floorf(x), y0f = floorf(y);
        float wx1 = x - x0f, wy1 = y - y0f;
        float wx0 = 1.0f - wx1, wy0 = 1.0f - wy1;
        int xi = (int)x0f, yi = (int)y0f;
        bool vx0 = (x0f >= 0.0f) && (x0f < 46.0f);
        bool vx1 = (x0f + 1.0f >= 0.0f) && (x0f + 1.0f < 46.0f);
        bool vy0 = (y0f >= 0.0f) && (y0f < 23.0f);
        bool vy1 = (y0f + 1.0f >= 0.0f) && (y0f + 1.0f < 23.0f);
        int xc0 = min(max(xi, 0), WV - 1), xc1 = min(max(xi + 1, 0), WV - 1);
        int yc0 = min(max(yi, 0), HV - 1), yc1 = min(max(yi + 1, 0), HV - 1);
        float w00 = (vx0 && vy0) ? wx0 * wy0 : 0.0f;
        float w10 = (vx1 && vy0) ? wx1 * wy0 : 0.0f;
        float w01 = (vx0 && vy1) ? wx0 * wy1 : 0.0f;
        float w11 = (vx1 && vy1) ? wx1 * wy1 : 0.0f;
        int ip00 = yc0 * WV + xc0, ip10 = yc0 * WV + xc1;
        int ip01 = yc1 * WV + xc0, ip11 = yc1 * WV + xc1;

        g_ip[t][0] = ip00 * (C_ * 2); g_ip[t][1] = ip10 * (C_ * 2);   // byte offsets
        g_ip[t][2] = ip01 * (C_ * 2); g_ip[t][3] = ip11 * (C_ * 2);
        __half hw0 = __float2half(w00 * at);
        __half hw1 = __float2half(w10 * at);
        __half hw2 = __float2half(w01 * at);
        __half hw3 = __float2half(w11 * at);
        g_wh[t][0] = __halves2half2(hw0, hw0);
        g_wh[t][1] = __halves2half2(hw1, hw1);
        g_wh[t][2] = __halves2half2(hw2, hw2);
        g_wh[t][3] = __halves2half2(hw3, hw3);

        // quad S32 load: slot[ip] = (S[ip], S[ip+1], S[ip+WV], S[ip+WV+1])
        const float4* Sb = (const float4*)S32Q + (size_t)b * NPIX * HEADS;
        float4 sq = Sb[ip00 * HEADS + h];
        float s10 = (ip10 == ip00) ? sq.x : sq.y;
        float s01 = (ip01 == ip00) ? sq.x : sq.z;
        float hi0 = (ip01 == ip00) ? sq.y : sq.w;
        float s11 = (ip11 == ip01) ? s01 : hi0;
        float samp = w00 * sq.x + w10 * s10 + w01 * s01 + w11 * s11;
        float contrib = at * samp;
        #pragma unroll
        for (int s2 = 16; s2; s2 >>= 1) contrib += __shfl_down(contrib, s2, 32);
        if (r == 0) logits_sh[v] = contrib;
    }
    __syncthreads();                                   // barrier 1 (A -> B)

    // ---- lanes 0..7 (f32): argmax + gap test + softmax weights
    if (t < 8) {
        float m = logits_sh[0]; int am = 0;
        #pragma unroll
        for (int v2 = 1; v2 < NV; ++v2) {
            float lv = logits_sh[v2];
            if (lv > m) { m = lv; am = v2; }
        }
        float e = expf(logits_sh[t] - m);
        float ssum = e;
        ssum += __shfl_xor(ssum, 1, 8);
        ssum += __shfl_xor(ssum, 2, 8);
        ssum += __shfl_xor(ssum, 4, 8);
        wf_sh[t] = e / ssum;
        if (t == 0) {
            amax_out[row] = (float)am;
            float m2 = -1e30f;
            #pragma unroll
            for (int v2 = 0; v2 < NV; ++v2) {
                float lv = logits_sh[v2];
                if (v2 != am && lv > m2) m2 = lv;
            }
            float thr = 1e-4f * fmaxf(1.0f, fabsf(m));
            if ((m - m2) < thr) {
                int idx = atomicAdd(cnt, 1);
                list[idx] = row;
            }
        }
    }

    // ---- phase B: 8 groups x 32 threads; group g = v; 8 channels/thread; packed f16 FMA
    {
        int g = t >> 5, lt = t & 31;
        int c0 = lt * 8;
        int c2 = c0 * 2;               // channel byte offset
        int hb = lt >> 2;
        const char* vb = (const char*)(VW + (size_t)b * NPIX * C_);
        __half2 h01 = __float2half2_rn(0.f);
        __half2 h23 = h01, h45 = h01, h67 = h01;
        #pragma unroll
        for (int pp = 0; pp < 2; ++pp) {
            int e0 = g * 32 + hb * 4 + pp * 2;         // entry (v=g, h=hb, p=pp*2); +1 -> p+1
            const int4   ipA = *reinterpret_cast<const int4*>(g_ip[e0]);
            const uint4  whA = *reinterpret_cast<const uint4*>(g_wh[e0]);
            const int4   ipB = *reinterpret_cast<const int4*>(g_ip[e0 + 1]);
            const uint4  whB = *reinterpret_cast<const uint4*>(g_wh[e0 + 1]);
            const uint4 uA0 = *reinterpret_cast<const uint4*>(vb + (ipA.x + c2));
            const uint4 uA1 = *reinterpret_cast<const uint4*>(vb + (ipA.y + c2));
            const uint4 uA2 = *reinterpret_cast<const uint4*>(vb + (ipA.z + c2));
            const uint4 uA3 = *reinterpret_cast<const uint4*>(vb + (ipA.w + c2));
            const uint4 uB0 = *reinterpret_cast<const uint4*>(vb + (ipB.x + c2));
            const uint4 uB1 = *reinterpret_cast<const uint4*>(vb + (ipB.y + c2));
            const uint4 uB2 = *reinterpret_cast<const uint4*>(vb + (ipB.z + c2));
            const uint4 uB3 = *reinterpret_cast<const uint4*>(vb + (ipB.w + c2));
            #define CORNER(WHU, U) { \
                const __half2 wh = *reinterpret_cast<const __half2*>(&WHU); \
                h01 = __hfma2(wh, *reinterpret_cast<const __half2*>(&U.x), h01); \
                h23 = __hfma2(wh, *reinterpret_cast<const __half2*>(&U.y), h23); \
                h45 = __hfma2(wh, *reinterpret_cast<const __half2*>(&U.z), h45); \
                h67 = __hfma2(wh, *reinterpret_cast<const __half2*>(&U.w), h67); }
            CORNER(whA.x, uA0)
            CORNER(whA.y, uA1)
            CORNER(whA.z, uA2)
            CORNER(whA.w, uA3)
            CORNER(whB.x, uB0)
            CORNER(whB.y, uB1)
            CORNER(whB.z, uB2)
            CORNER(whB.w, uB3)
            #undef CORNER
        }
        float a0 = __low2float(h01), a1 = __high2float(h01);
        float a2 = __low2float(h23), a3 = __high2float(h23);
        float a4 = __low2float(h45), a5 = __high2float(h45);
        float a6 = __low2float(h67), a7 = __high2float(h67);
        float4 s0v = {a0, a1, a2, a3}, s1v = {a4, a5, a6, a7};
        *reinterpret_cast<float4*>(&red[g][c0])     = s0v;
        *reinterpret_cast<float4*>(&red[g][c0 + 4]) = s1v;
    }
    __syncthreads();                                   // barrier 2 (B -> epilogue)
    float O = 0.f;
    #pragma unroll
    for (int g8 = 0; g8 < NV; ++g8) O = fmaf(wf_sh[g8], red[g8][t], O);
    out[(size_t)row * C_ + t] = O + b_pre + 2.0f * q_pre;
}

// ---------------- exact replication (compacted: grid-stride over flagged list) ----------------
__global__ void __launch_bounds__(256) exact_kernel(
        const float* __restrict__ v2d, const float* __restrict__ offn,
        const float* __restrict__ attn, const float* __restrict__ grd_col,
        const float* __restrict__ grd_row, const float* __restrict__ Wout,
        const float* __restrict__ bout, const float* __restrict__ Wp,
        const float* __restrict__ bp, const float* __restrict__ query,
        const int* __restrict__ cnt, const int* __restrict__ list,
        float* __restrict__ amax_out) {
#pragma clang fp contract(off)
    int n = *cnt;
    int t = threadIdx.x;
    int h = t >> 5;
    __shared__ float s_off[64];
    __shared__ float s_attn[32];
    __shared__ float wp_lds[C_];
    __shared__ float out_l[NV][C_ + 1];
    __shared__ float bevs_l[NV][C_ + 1];
    __shared__ float lgs[NV];
    wp_lds[t] = Wp[t];

    for (int i = blockIdx.x; i < n; i += gridDim.x) {
        int row = list[i];
        int b = row >> 12;
        int q = row & (NQ - 1);
        if (t < 64)      s_off[t]       = offn[(size_t)row * 64 + t];
        else if (t < 96) s_attn[t - 64] = attn[(size_t)row * 32 + (t - 64)];
        __syncthreads();

        const float* vb = v2d + (size_t)b * NPIX * C_;
        #pragma unroll
        for (int v = 0; v < NV; ++v) {
            float refx = grd_col[q * NV + v];
            float refy = grd_row[q * NV + v];
            float acc = 0.0f;
            #pragma unroll
            for (int p = 0; p < PTS; ++p) {
                float lx = refx + s_off[h * 8 + p * 2 + 0];
                float ly = refy + s_off[h * 8 + p * 2 + 1];
                float x = lx * 46.0f - 0.5f;
                float y = ly * 23.0f - 0.5f;
                float x0f = floorf(x), y0f = floorf(y);
                float wx1 = x - x0f, wy1 = y - y0f;
                float wx0 = 1.0f - wx1, wy0 = 1.0f - wy1;
                int xi = (int)x0f, yi = (int)y0f;
                bool vx0 = (x0f >= 0.0f) && (x0f < 46.0f);
                bool vx1 = (x0f + 1.0f >= 0.0f) && (x0f + 1.0f < 46.0f);
                bool vy0 = (y0f >= 0.0f) && (y0f < 23.0f);
                bool vy1 = (y0f + 1.0f >= 0.0f) && (y0f + 1.0f < 23.0f);
                int xc0 = min(max(xi, 0), WV - 1), xc1 = min(max(xi + 1, 0), WV - 1);
                int yc0 = min(max(yi, 0), HV - 1), yc1 = min(max(yi + 1, 0), HV - 1);
                float g00 = (vx0 && vy0) ? vb[(yc0 * WV + xc0) * C_ + t] : 0.0f;
                float g10 = (vx1 && vy0) ? vb[(yc0 * WV + xc1) * C_ + t] : 0.0f;
                float g01 = (vx0 && vy1) ? vb[(yc1 * WV + xc0) * C_ + t] : 0.0f;
                float g11 = (vx1 && vy1) ? vb[(yc1 * WV + xc1) * C_ + t] : 0.0f;
                float t00 = g00 * (wx0 * wy0);
                float t10 = g10 * (wx1 * wy0);
                float t01 = g01 * (wx0 * wy1);
                float t11 = g11 * (wx1 * wy1);
                float samp = ((t00 + t10) + t01) + t11;
                float pr = s_attn[h * 4 + p] * samp;
                acc = acc + pr;
            }
            out_l[v][t] = acc;
        }
        __syncthreads();

        float bacc[NV];
        #pragma unroll
        for (int v = 0; v < NV; ++v) bacc[v] = 0.f;
        for (int i2 = 0; i2 < C_; ++i2) {
            float w_it = Wout[i2 * C_ + t];
            #pragma unroll
            for (int v = 0; v < NV; ++v) bacc[v] = __builtin_fmaf(out_l[v][i2], w_it, bacc[v]);
        }
        float bo_t = bout[t];
        float qv = query[(size_t)row * C_ + t];
        #pragma unroll
        for (int v = 0; v < NV; ++v) bevs_l[v][t] = (bacc[v] + bo_t) + qv;
        __syncthreads();

        if (t < NV) {
            float lv = 0.f;
            for (int c = 0; c < C_; ++c) lv = __builtin_fmaf(bevs_l[t][c], wp_lds[c], lv);
            lgs[t] = lv + bp[0];
        }
        __syncthreads();

        if (t == 0) {
            float l[NV];
            #pragma unroll
            for (int v = 0; v < NV; ++v) l[v] = lgs[v];
            float m = l[0];
            #pragma unroll
            for (int v = 1; v < NV; ++v) m = fmaxf(m, l[v]);
            float e[NV];
            #pragma unroll
            for (int v = 0; v < NV; ++v) e[v] = expf(l[v] - m);
            float s = ((e[0] + e[1]) + (e[2] + e[3])) + ((e[4] + e[5]) + (e[6] + e[7]));
            float w[NV];
            #pragma unroll
            for (int v = 0; v < NV; ++v) w[v] = e[v] / s;
            int am = 0; float wm = w[0];
            #pragma unroll
            for (int v = 1; v < NV; ++v) { if (w[v] > wm) { wm = w[v]; am = v; } }
            amax_out[row] = (float)am;
        }
        __syncthreads();
    }
}

extern "C" void kernel_launch(void* const* d_in, const int* in_sizes, int n_in,
                              void* d_out, int out_size, void* d_ws, size_t ws_size,
                              hipStream_t stream) {
    const float* query   = (const float*)d_in[0];
    const float* value   = (const float*)d_in[1];
    const float* grd_col = (const float*)d_in[2];
    const float* grd_row = (const float*)d_in[3];
    const float* Wv      = (const float*)d_in[4];
    const float* bv      = (const float*)d_in[5];
    const float* Wo      = (const float*)d_in[6];
    const float* bo      = (const float*)d_in[7];
    const float* Wa      = (const float*)d_in[8];
    const float* ba      = (const float*)d_in[9];
    const float* Wout    = (const float*)d_in[10];
    const float* bout    = (const float*)d_in[11];
    const float* Wp      = (const float*)d_in[12];
    const float* bp      = (const float*)d_in[13];

    float* out  = (float*)d_out;
    float* ws   = (float*)d_ws;
    float* offn = ws;                                        // 32768*64 f32
    float* attn = offn + (size_t)NROW * 64;                  // 32768*32 f32
    float* v2d  = attn + (size_t)NROW * 32;                  // 8464*256 f32
    float* wp2f = v2d + (size_t)BS * NPIX * C_;              // 256 f32
    float* S32Q = wp2f + C_;                                 // 8464*8 float4 = 270848 f32
    int* cnt    = (int*)(S32Q + (size_t)BS * NPIX * HEADS * 4); // 1 int (padded to 4)
    int* list   = cnt + 4;                                   // 32768 int
    ushort_t* VW = (ushort_t*)(list + NROW);                 // 8464*256 fp16
    float* WvWout = (float*)(VW + (size_t)BS * NPIX * C_);   // 256*256 f32
    float* bvW    = WvWout + C_ * C_;                        // 256 f32
    float* amax = out + (size_t)NROW * C_;

    prep_kernel<<<65, 256, 0, stream>>>(Wout, Wp, Wv, bv, WvWout, wp2f, bvW, cnt);
    proj_kernel<<<NVBLK2 + NQBLK, 256, 0, stream>>>(value, Wv, bv, WvWout, bvW, wp2f,
                                                    query, Wo, bo, Wa, ba,
                                                    v2d, VW, S32Q, offn, attn);
    fused_kernel<<<NROW, 256, 0, stream>>>(VW, offn, attn, grd_col, grd_row, S32Q,
                                           query, bout, out, amax, cnt, list);
    exact_kernel<<<512, 256, 0, stream>>>(v2d, offn, attn, grd_col, grd_row,
                                          Wout, bout, Wp, bp, query, cnt, list, amax);
}